// Round 5
// baseline (421.039 us; speedup 1.0000x reference)
//
#include <hip/hip_runtime.h>
#include <hip/hip_bf16.h>
#include <float.h>

#define IN_F 256
#define HD   128   // H*D
#define NH   4
#define GM   128   // gemm rows per tile
#define CHUNK 8192 // edges per histogram/scatter chunk
#define BNODES 256 // nodes per bucket (bucket = dst >> 8)
#define NCSR 242   // CSR-role blocks (first NCSR block ids; must be << min residency)

typedef __bf16 bf16x8 __attribute__((ext_vector_type(8)));
typedef float  f32x4  __attribute__((ext_vector_type(4)));

__device__ __forceinline__ bf16x8 cvt8(const float4 a, const float4 b) {
    bf16x8 r;
    r[0] = (__bf16)a.x; r[1] = (__bf16)a.y; r[2] = (__bf16)a.z; r[3] = (__bf16)a.w;
    r[4] = (__bf16)b.x; r[5] = (__bf16)b.y; r[6] = (__bf16)b.z; r[7] = (__bf16)b.w;
    return r;
}

// ---------------------------------------------------------------------------
// init_k: pre-swizzle W into MFMA-fragment-major bf16 (64 KB, L2-resident):
//   wfrag[((ks*8+ct)*64+lane)*8..+7] = B[ct*16+(lane&15)][ks*32+(lane>>4)*8+j]
// Also zeroes the mega-kernel control words (sub-barrier counter + bucket
// cursor) -- replaces a hipMemsetAsync dispatch.
// ---------------------------------------------------------------------------
__global__ __launch_bounds__(256) void init_k(const float* __restrict__ w,
                                              __bf16* __restrict__ wfrag,
                                              int* __restrict__ ctrl) {
    const int t = threadIdx.x;
    if (t < 2) ctrl[t] = 0;
    const int col = t >> 1;              // 0..127
    const int k0 = (t & 1) * 128;
    const int ct = col >> 4;
    const float* wp = w + (size_t)col * IN_F + k0;
#pragma unroll
    for (int kk = 0; kk < 128; kk += 8) {
        const float4 v0 = *(const float4*)(wp + kk);
        const float4 v1 = *(const float4*)(wp + kk + 4);
        const int k = k0 + kk;
        const int ks = k >> 5;
        const int lane = (col & 15) + (((k >> 3) & 3) << 4);
        *(bf16x8*)(wfrag + ((size_t)(ks * 8 + ct) * 64 + lane) * 8) = cvt8(v0, v1);
    }
}

// ---------------------------------------------------------------------------
// Sub-barrier among the NCSR CSR-role blocks only. Monotonic counter; target
// = NCSR * phase. Release on arrival flushes this XCD's L2 (prior plain
// stores become visible); relaxed spin avoids hammering cache invalidates
// while co-resident GEMM blocks run; one acquire after passing invalidates
// L1/L2 so subsequent reads see other XCDs' data.
// Deadlock-safety: CSR blocks are block ids [0, NCSR) -> dispatched first,
// and NCSR=242 is below worst-case device residency (>=256 at 1 block/CU),
// so all participants are guaranteed co-resident.
// ---------------------------------------------------------------------------
__device__ __forceinline__ void subbar(int* bar, int target) {
    __syncthreads();
    if (threadIdx.x == 0) {
        __hip_atomic_fetch_add(bar, 1, __ATOMIC_ACQ_REL, __HIP_MEMORY_SCOPE_AGENT);
        while (__hip_atomic_load(bar, __ATOMIC_RELAXED, __HIP_MEMORY_SCOPE_AGENT) < target)
            __builtin_amdgcn_s_sleep(16);
        (void)__hip_atomic_load(bar, __ATOMIC_ACQUIRE, __HIP_MEMORY_SCOPE_AGENT);
    }
    __syncthreads();
}

// ---------------------------------------------------------------------------
// mega: R4 post-mortem showed gemm (78us) runs with ALL pipes idle (MfmaUtil
// 3%, VALU 5%, HBM 13%) while ~175us of wall time sat in 3 small CSR
// dispatches + launch gaps. So: run the ENTIRE CSR chain in blocks [0,NCSR)
// (hist -> chunkscan+bucket-alloc -> bscatter -> csr, separated by subbar),
// overlapped under the latency-bound GEMM in blocks [NCSR, NCSR+ntiles).
// GEMM tile code is byte-identical to R4's (isolated variable).
// mfma_f32_16x16x32_bf16; C/D: col=lane&15, row=(lane>>4)*4+reg (verified R2).
// ---------------------------------------------------------------------------
__global__ __launch_bounds__(256) void mega(const float* __restrict__ feat,
                                            const __bf16* __restrict__ wfrag,
                                            const float* __restrict__ attn_l,
                                            const float* __restrict__ attn_r,
                                            const int* __restrict__ src,
                                            const int* __restrict__ dst,
                                            __bf16* __restrict__ ft,
                                            float* __restrict__ el,
                                            float* __restrict__ er,
                                            int* __restrict__ cnt,
                                            int* __restrict__ total,
                                            int* __restrict__ bstart,
                                            int2* __restrict__ epair,
                                            int* __restrict__ deg,
                                            int* __restrict__ off,
                                            int* __restrict__ ssrc,
                                            int* __restrict__ ctrl,
                                            int N, int E,
                                            int ntiles, int nchunk, int nbucket) {
    const int t = threadIdx.x;

    if (blockIdx.x < NCSR) {
        // =================== CSR role ===================
        __shared__ int cnt_l[512];   // hist counters / bscatter cursors
        __shared__ int sl[256];      // scan scratch
        __shared__ int cl[256];      // csr node histogram
        __shared__ int lcur[256];    // csr local cursors
        const int cid = blockIdx.x;
        int* bar  = ctrl;
        int* gcur = ctrl + 1;

        // ---- phase 1: per-chunk coarse histogram of dst>>8 ----
        for (int c = cid; c < nchunk; c += NCSR) {
            for (int j = t; j < nbucket; j += 256) cnt_l[j] = 0;
            __syncthreads();
            const int e0 = c * CHUNK;
#pragma unroll
            for (int k = 0; k < CHUNK / 256; ++k) {
                const int i = e0 + k * 256 + t;
                if (i < E) atomicAdd(&cnt_l[dst[i] >> 8], 1);
            }
            __syncthreads();
            for (int j = t; j < nbucket; j += 256) cnt[(size_t)c * nbucket + j] = cnt_l[j];
            __syncthreads();
        }
        subbar(bar, NCSR * 1);

        // ---- phase 2: per-bucket scan over chunks + bucket segment alloc ----
        // cnt[c][b] <- exclusive prefix; total[b] = bucket size;
        // bstart[b] allocated via one global atomicAdd per bucket (order of
        // bucket segments is arbitrary -- only consistency matters).
        for (int b = cid; b < nbucket; b += NCSR) {
            const int x = (t < nchunk) ? cnt[(size_t)t * nbucket + b] : 0;
            sl[t] = x;
            __syncthreads();
            int v = x;
            for (int s = 1; s < 256; s <<= 1) {
                const int add = (t >= s) ? sl[t - s] : 0;
                __syncthreads();
                v += add;
                sl[t] = v;
                __syncthreads();
            }
            if (t < nchunk) cnt[(size_t)t * nbucket + b] = v - x;
            if (t == 255) {
                total[b] = v;
                bstart[b] = atomicAdd(gcur, v);
            }
            __syncthreads();
        }
        subbar(bar, NCSR * 2);

        // ---- phase 3: coarse scatter into bucket-major (src,dst) pairs ----
        for (int c = cid; c < nchunk; c += NCSR) {
            for (int j = t; j < 512; j += 256)
                cnt_l[j] = (j < nbucket) ? bstart[j] + cnt[(size_t)c * nbucket + j] : 0;
            __syncthreads();
            const int e0 = c * CHUNK;
#pragma unroll
            for (int k = 0; k < CHUNK / 256; ++k) {
                const int i = e0 + k * 256 + t;
                if (i < E) {
                    const int d = dst[i];
                    const int p = atomicAdd(&cnt_l[d >> 8], 1);
                    epair[p] = make_int2(src[i], d);
                }
            }
            __syncthreads();
        }
        subbar(bar, NCSR * 3);

        // ---- phase 4: per-bucket CSR finalize (deg, absolute off, ssrc) ----
        for (int b = cid; b < nbucket; b += NCSR) {
            const int seg0 = bstart[b];
            const int tb   = total[b];
            cl[t] = 0;
            __syncthreads();
            for (int i = seg0 + t; i < seg0 + tb; i += 256)
                atomicAdd(&cl[epair[i].y & 255], 1);
            __syncthreads();
            const int x2 = cl[t];
            sl[t] = x2;
            __syncthreads();
            int v2 = x2;
            for (int s = 1; s < 256; s <<= 1) {
                const int add = (t >= s) ? sl[t - s] : 0;
                __syncthreads();
                v2 += add;
                sl[t] = v2;
                __syncthreads();
            }
            const int loff = v2 - x2;
            const int node = b * BNODES + t;
            if (node < N) {
                deg[node] = x2;
                off[node] = seg0 + loff;    // ABSOLUTE
            }
            lcur[t] = loff;
            __syncthreads();
            for (int i = seg0 + t; i < seg0 + tb; i += 256) {
                const int2 e = epair[i];
                const int p = atomicAdd(&lcur[e.y & 255], 1);
                ssrc[seg0 + p] = e.x;
            }
            __syncthreads();
        }
        return;
    }

    // =================== GEMM role (identical to R4) ===================
    const int wv = t >> 6;
    const int lane = t & 63;
    const int frow = lane & 15;
    const int fq   = lane >> 4;          // k-quarter 0..3

    float alw[8], arw[8];
#pragma unroll
    for (int ct = 0; ct < 8; ++ct) {
        alw[ct] = attn_l[ct * 16 + frow];
        arw[ct] = attn_r[ct * 16 + frow];
    }

    const int gstride = gridDim.x - NCSR;
    for (int tile = blockIdx.x - NCSR; tile < ntiles; tile += gstride) {
        const int row0 = tile * GM;
        const int r0 = row0 + wv * 32 + frow;        // mt=0 fragment row
        const int r1 = r0 + 16;                      // mt=1 fragment row
        const bool ok0 = r0 < N;
        const bool ok1 = r1 < N;
        const float* fA0 = feat + (size_t)r0 * IN_F + fq * 8;
        const float* fA1 = feat + (size_t)r1 * IN_F + fq * 8;
        const __bf16* wfl = wfrag + (size_t)lane * 8;

        f32x4 acc[2][8];
#pragma unroll
        for (int mt = 0; mt < 2; ++mt)
#pragma unroll
            for (int ct = 0; ct < 8; ++ct) acc[mt][ct] = {0.f, 0.f, 0.f, 0.f};

#pragma unroll
        for (int ks = 0; ks < 8; ++ks) {
            bf16x8 af0, af1;
            if (ok0) {
                const float4 a = *(const float4*)(fA0 + ks * 32);
                const float4 b = *(const float4*)(fA0 + ks * 32 + 4);
                af0 = cvt8(a, b);
            } else {
#pragma unroll
                for (int i = 0; i < 8; ++i) af0[i] = (__bf16)0.f;
            }
            if (ok1) {
                const float4 a = *(const float4*)(fA1 + ks * 32);
                const float4 b = *(const float4*)(fA1 + ks * 32 + 4);
                af1 = cvt8(a, b);
            } else {
#pragma unroll
                for (int i = 0; i < 8; ++i) af1[i] = (__bf16)0.f;
            }
#pragma unroll
            for (int ct = 0; ct < 8; ++ct) {
                const bf16x8 bfrag = *(const bf16x8*)(wfl + (size_t)(ks * 8 + ct) * 512);
                acc[0][ct] = __builtin_amdgcn_mfma_f32_16x16x32_bf16(af0, bfrag, acc[0][ct], 0, 0, 0);
                acc[1][ct] = __builtin_amdgcn_mfma_f32_16x16x32_bf16(af1, bfrag, acc[1][ct], 0, 0, 0);
            }
        }

        // ---- epilogue: ft stores (row = (lane>>4)*4 + reg, col = ct*16 + frow) ----
        const int rb = row0 + wv * 32 + (lane >> 4) * 4;
        if (row0 + GM <= N) {
#pragma unroll
            for (int mt = 0; mt < 2; ++mt)
#pragma unroll
                for (int ct = 0; ct < 8; ++ct)
#pragma unroll
                    for (int reg = 0; reg < 4; ++reg) {
                        const int m = rb + mt * 16 + reg;
                        ft[(size_t)m * HD + ct * 16 + frow] = (__bf16)acc[mt][ct][reg];
                    }
        } else {
#pragma unroll
            for (int mt = 0; mt < 2; ++mt)
#pragma unroll
                for (int ct = 0; ct < 8; ++ct)
#pragma unroll
                    for (int reg = 0; reg < 4; ++reg) {
                        const int m = rb + mt * 16 + reg;
                        if (m < N) ft[(size_t)m * HD + ct * 16 + frow] = (__bf16)acc[mt][ct][reg];
                    }
        }

        // ---- fused el/er epilogue ----
#pragma unroll
        for (int mt = 0; mt < 2; ++mt) {
#pragma unroll
            for (int reg = 0; reg < 4; ++reg) {
                float pl[4], pr[4];
#pragma unroll
                for (int h = 0; h < 4; ++h) {
                    const float v0 = acc[mt][2 * h][reg];
                    const float v1 = acc[mt][2 * h + 1][reg];
                    pl[h] = v0 * alw[2 * h] + v1 * alw[2 * h + 1];
                    pr[h] = v0 * arw[2 * h] + v1 * arw[2 * h + 1];
                }
#pragma unroll
                for (int s = 1; s < 16; s <<= 1) {
#pragma unroll
                    for (int h = 0; h < 4; ++h) {
                        pl[h] += __shfl_xor(pl[h], s);
                        pr[h] += __shfl_xor(pr[h], s);
                    }
                }
                if (frow == 0) {
                    const int r = row0 + wv * 32 + mt * 16 + (lane >> 4) * 4 + reg;
                    if (r < N) {
                        *(float4*)(el + (size_t)r * NH) = make_float4(pl[0], pl[1], pl[2], pl[3]);
                        *(float4*)(er + (size_t)r * NH) = make_float4(pr[0], pr[1], pr[2], pr[3]);
                    }
                }
            }
        }
    }
}

// ---------------------------------------------------------------------------
// Aggregation: one wave per dst node. UNCHANGED from R4 (measured at its
// gather-pattern roofline: ~245 MB beyond-L2 traffic at ~3.9 TB/s, ~77us).
// ---------------------------------------------------------------------------
__global__ __launch_bounds__(64) void aggregate_k(const __bf16* __restrict__ ft,
                                                  const float* __restrict__ el,
                                                  const float* __restrict__ er,
                                                  const int* __restrict__ deg,
                                                  const int* __restrict__ off,
                                                  const int* __restrict__ ssrc,
                                                  float* __restrict__ out, int N) {
    const int n = blockIdx.x;
    const int lane = threadIdx.x;
    const int il = lane & 15;       // feature group: f = il*8 .. il*8+7
    const int q  = lane >> 4;       // edge slot within group of 4
    const int h  = il >> 2;         // head of this feature group
    float4* outp = (float4*)(out + (size_t)n * HD);
    const int dn = deg[n];
    if (dn == 0) {
        if (q < 2) outp[il * 2 + q] = make_float4(0.f, 0.f, 0.f, 0.f);
        return;
    }
    const int start = off[n];
    const float4 er4 = *(const float4*)(er + (size_t)n * NH);

    __shared__ float a_lds[64 * NH];
    __shared__ int   s_lds[64];
    float4 ssum = make_float4(0.f, 0.f, 0.f, 0.f);
    float acc[8];
#pragma unroll
    for (int i = 0; i < 8; ++i) acc[i] = 0.f;

    for (int c0 = 0; c0 < dn; c0 += 64) {
        const int j = c0 + lane;
        float4 a = make_float4(0.f, 0.f, 0.f, 0.f);
        int sv = 0;
        if (j < dn) {
            sv = ssrc[start + j];
            float4 e = *(const float4*)(el + (size_t)sv * NH);
            e.x += er4.x; e.y += er4.y; e.z += er4.z; e.w += er4.w;
            e.x = e.x >= 0.f ? e.x : 0.2f * e.x;
            e.y = e.y >= 0.f ? e.y : 0.2f * e.y;
            e.z = e.z >= 0.f ? e.z : 0.2f * e.z;
            e.w = e.w >= 0.f ? e.w : 0.2f * e.w;
            a.x = __expf(e.x); a.y = __expf(e.y);
            a.z = __expf(e.z); a.w = __expf(e.w);
            ssum.x += a.x; ssum.y += a.y; ssum.z += a.z; ssum.w += a.w;
        }
        s_lds[lane] = sv;
        *(float4*)(a_lds + lane * NH) = a;
        __syncthreads();
        const int cnt2 = min(64, dn - c0);
        for (int j2 = 0; j2 < cnt2; j2 += 8) {   // 8 edges/iter (2 groups of 4)
            const int e0 = j2 + q;
            const int e1 = j2 + 4 + q;
            const int sv0 = s_lds[e0];
            const int sv1 = s_lds[e1];
            const float a0 = a_lds[e0 * NH + h];
            const float a1 = a_lds[e1 * NH + h];
            const bf16x8 f0 = *(const bf16x8*)(ft + (size_t)sv0 * HD + il * 8);
            const bf16x8 f1 = *(const bf16x8*)(ft + (size_t)sv1 * HD + il * 8);
#pragma unroll
            for (int k = 0; k < 8; ++k) acc[k] = fmaf(a0, (float)f0[k], acc[k]);
#pragma unroll
            for (int k = 0; k < 8; ++k) acc[k] = fmaf(a1, (float)f1[k], acc[k]);
        }
        __syncthreads();
    }
#pragma unroll
    for (int s = 1; s < 64; s <<= 1) {
        ssum.x += __shfl_xor(ssum.x, s);
        ssum.y += __shfl_xor(ssum.y, s);
        ssum.z += __shfl_xor(ssum.z, s);
        ssum.w += __shfl_xor(ssum.w, s);
    }
#pragma unroll
    for (int k = 0; k < 8; ++k) {
        acc[k] += __shfl_xor(acc[k], 16);
        acc[k] += __shfl_xor(acc[k], 32);
    }
    const float sumh = (h == 0) ? ssum.x : (h == 1) ? ssum.y : (h == 2) ? ssum.z : ssum.w;
    const float inv = 1.f / sumh;
    if (q < 2) {
        const int b = q * 4;
        outp[il * 2 + q] = make_float4(acc[b] * inv, acc[b + 1] * inv,
                                       acc[b + 2] * inv, acc[b + 3] * inv);
    }
}

// ---------------------------------------------------------------------------
extern "C" void kernel_launch(void* const* d_in, const int* in_sizes, int n_in,
                              void* d_out, int out_size, void* d_ws, size_t ws_size,
                              hipStream_t stream) {
    const float* feat   = (const float*)d_in[0];
    const float* fc_w   = (const float*)d_in[1];
    const float* attn_l = (const float*)d_in[2];
    const float* attn_r = (const float*)d_in[3];
    const int*   src    = (const int*)d_in[4];
    const int*   dst    = (const int*)d_in[5];
    const int N = in_sizes[0] / IN_F;
    const int E = in_sizes[4];
    float* out = (float*)d_out;

    const int ntiles  = (N + GM - 1) / GM;          // 782
    const int nchunk  = (E + CHUNK - 1) / CHUNK;    // 196 (<=256 required)
    const int nbucket = (N + BNODES - 1) / BNODES;  // 391 (<=512 required)

    char* wp = (char*)d_ws;
    __bf16* ft = (__bf16*)wp; wp += (size_t)N * HD * 2;           // 25.6 MB
    float* el  = (float*)wp; wp += (size_t)N * NH * 4;            // 1.6 MB
    float* er  = (float*)wp; wp += (size_t)N * NH * 4;            // 1.6 MB
    int* deg   = (int*)wp;   wp += (size_t)N * 4;                 // 0.4 MB
    int* off   = (int*)wp;   wp += (size_t)N * 4;                 // 0.4 MB
    int* cnt   = (int*)wp;   wp += (size_t)nchunk * nbucket * 4;  // ~0.3 MB
    int* total = (int*)wp;   wp += 2048;
    int* bstart= (int*)wp;   wp += 2048;
    int* ctrl  = (int*)wp;   wp += 64;                            // [bar, gcur]
    int* ssrc  = (int*)wp;   wp += (size_t)E * 4;                 // 6.4 MB
    int2* epair = (int2*)wp; wp += (size_t)E * 8;                 // 12.8 MB
    __bf16* wfrag = (__bf16*)wp; wp += (size_t)HD * IN_F * 2;     // 64 KB

    init_k<<<dim3(1), dim3(256), 0, stream>>>(fc_w, wfrag, ctrl);
    mega<<<dim3(NCSR + ntiles), dim3(256), 0, stream>>>(
        feat, wfrag, attn_l, attn_r, src, dst, ft, el, er,
        cnt, total, bstart, epair, deg, off, ssrc, ctrl,
        N, E, ntiles, nchunk, nbucket);
    aggregate_k<<<dim3(N), dim3(64), 0, stream>>>(ft, el, er, deg, off, ssrc, out, N);
}

// Round 6
// 396.204 us; speedup vs baseline: 1.0627x; 1.0627x over previous
//
#include <hip/hip_runtime.h>
#include <hip/hip_bf16.h>
#include <float.h>

#define IN_F 256
#define HD   128   // H*D
#define NH   4
#define GM   128   // gemm rows per tile
#define CHUNK 8192 // edges per histogram/scatter chunk
#define BNODES 256 // nodes per bucket (bucket = dst >> 8)
#define NCSR 256   // csr_chain blocks; <= CU count -> co-residency guaranteed

typedef __bf16 bf16x8 __attribute__((ext_vector_type(8)));
typedef float  f32x4  __attribute__((ext_vector_type(4)));

__device__ __forceinline__ bf16x8 cvt8(const float4 a, const float4 b) {
    bf16x8 r;
    r[0] = (__bf16)a.x; r[1] = (__bf16)a.y; r[2] = (__bf16)a.z; r[3] = (__bf16)a.w;
    r[4] = (__bf16)b.x; r[5] = (__bf16)b.y; r[6] = (__bf16)b.z; r[7] = (__bf16)b.w;
    return r;
}

// ---------------------------------------------------------------------------
// init_k: pre-swizzle W into MFMA-fragment-major bf16 (64 KB, L2-resident):
//   wfrag[((ks*8+ct)*64+lane)*8..+7] = B[ct*16+(lane&15)][ks*32+(lane>>4)*8+j]
// Also zeroes the csr_chain control words (sub-barrier counter + bucket cursor).
// ---------------------------------------------------------------------------
__global__ __launch_bounds__(256) void init_k(const float* __restrict__ w,
                                              __bf16* __restrict__ wfrag,
                                              int* __restrict__ ctrl) {
    const int t = threadIdx.x;
    if (t < 2) ctrl[t] = 0;
    const int col = t >> 1;              // 0..127
    const int k0 = (t & 1) * 128;
    const int ct = col >> 4;
    const float* wp = w + (size_t)col * IN_F + k0;
#pragma unroll
    for (int kk = 0; kk < 128; kk += 8) {
        const float4 v0 = *(const float4*)(wp + kk);
        const float4 v1 = *(const float4*)(wp + kk + 4);
        const int k = k0 + kk;
        const int ks = k >> 5;
        const int lane = (col & 15) + (((k >> 3) & 3) << 4);
        *(bf16x8*)(wfrag + ((size_t)(ks * 8 + ct) * 64 + lane) * 8) = cvt8(v0, v1);
    }
}

// ---------------------------------------------------------------------------
// gemm_fused: VERBATIM R4 (measured 78.6us, 108 VGPR). Blocks [0,ntiles) =
// zero-LDS streaming MFMA GEMM + fused el/er; blocks [ntiles,+nchunk) =
// per-chunk LDS histogram of dst>>8 -> cnt[c][b].
// R5 post-mortem: merging the whole CSR chain into this kernel inflated
// VGPRs 108->240 (co-compiled role penalty), occupancy 18.7->11%, 214us.
// Roles with different register profiles must stay in separate kernels.
// mfma_f32_16x16x32_bf16; C/D: col=lane&15, row=(lane>>4)*4+reg (verified R2).
// ---------------------------------------------------------------------------
__global__ __launch_bounds__(256) void gemm_fused(const float* __restrict__ feat,
                                                  const __bf16* __restrict__ wfrag,
                                                  const float* __restrict__ attn_l,
                                                  const float* __restrict__ attn_r,
                                                  const int* __restrict__ dst,
                                                  __bf16* __restrict__ ft,
                                                  float* __restrict__ el,
                                                  float* __restrict__ er,
                                                  int* __restrict__ cnt,
                                                  int N, int E,
                                                  int ntiles, int nbucket) {
    const int t = threadIdx.x;

    if (blockIdx.x >= ntiles) {
        // ---- hist role: coarse bucket histogram for one edge chunk ----
        __shared__ int cnt_l[512];       // nbucket <= 512
        const int c = blockIdx.x - ntiles;
        for (int j = t; j < nbucket; j += 256) cnt_l[j] = 0;
        __syncthreads();
        const int e0 = c * CHUNK;
#pragma unroll
        for (int k = 0; k < CHUNK / 256; ++k) {
            const int i = e0 + k * 256 + t;
            if (i < E) atomicAdd(&cnt_l[dst[i] >> 8], 1);
        }
        __syncthreads();
        for (int j = t; j < nbucket; j += 256) cnt[(size_t)c * nbucket + j] = cnt_l[j];
        return;
    }

    // ---- GEMM role ----
    const int wv = t >> 6;
    const int lane = t & 63;
    const int frow = lane & 15;
    const int fq   = lane >> 4;          // k-quarter 0..3

    float alw[8], arw[8];
#pragma unroll
    for (int ct = 0; ct < 8; ++ct) {
        alw[ct] = attn_l[ct * 16 + frow];
        arw[ct] = attn_r[ct * 16 + frow];
    }

    const int row0 = blockIdx.x * GM;
    const int r0 = row0 + wv * 32 + frow;        // mt=0 fragment row
    const int r1 = r0 + 16;                      // mt=1 fragment row
    const bool ok0 = r0 < N;
    const bool ok1 = r1 < N;
    const float* fA0 = feat + (size_t)r0 * IN_F + fq * 8;
    const float* fA1 = feat + (size_t)r1 * IN_F + fq * 8;
    const __bf16* wfl = wfrag + (size_t)lane * 8;

    f32x4 acc[2][8];
#pragma unroll
    for (int mt = 0; mt < 2; ++mt)
#pragma unroll
        for (int ct = 0; ct < 8; ++ct) acc[mt][ct] = {0.f, 0.f, 0.f, 0.f};

#pragma unroll
    for (int ks = 0; ks < 8; ++ks) {
        bf16x8 af0, af1;
        if (ok0) {
            const float4 a = *(const float4*)(fA0 + ks * 32);
            const float4 b = *(const float4*)(fA0 + ks * 32 + 4);
            af0 = cvt8(a, b);
        } else {
#pragma unroll
            for (int i = 0; i < 8; ++i) af0[i] = (__bf16)0.f;
        }
        if (ok1) {
            const float4 a = *(const float4*)(fA1 + ks * 32);
            const float4 b = *(const float4*)(fA1 + ks * 32 + 4);
            af1 = cvt8(a, b);
        } else {
#pragma unroll
            for (int i = 0; i < 8; ++i) af1[i] = (__bf16)0.f;
        }
#pragma unroll
        for (int ct = 0; ct < 8; ++ct) {
            const bf16x8 bfrag = *(const bf16x8*)(wfl + (size_t)(ks * 8 + ct) * 512);
            acc[0][ct] = __builtin_amdgcn_mfma_f32_16x16x32_bf16(af0, bfrag, acc[0][ct], 0, 0, 0);
            acc[1][ct] = __builtin_amdgcn_mfma_f32_16x16x32_bf16(af1, bfrag, acc[1][ct], 0, 0, 0);
        }
    }

    // ---- epilogue: ft stores (row = (lane>>4)*4 + reg, col = ct*16 + frow) ----
    const int rb = row0 + wv * 32 + (lane >> 4) * 4;
    if (row0 + GM <= N) {
#pragma unroll
        for (int mt = 0; mt < 2; ++mt)
#pragma unroll
            for (int ct = 0; ct < 8; ++ct)
#pragma unroll
                for (int reg = 0; reg < 4; ++reg) {
                    const int m = rb + mt * 16 + reg;
                    ft[(size_t)m * HD + ct * 16 + frow] = (__bf16)acc[mt][ct][reg];
                }
    } else {
#pragma unroll
        for (int mt = 0; mt < 2; ++mt)
#pragma unroll
            for (int ct = 0; ct < 8; ++ct)
#pragma unroll
                for (int reg = 0; reg < 4; ++reg) {
                    const int m = rb + mt * 16 + reg;
                    if (m < N) ft[(size_t)m * HD + ct * 16 + frow] = (__bf16)acc[mt][ct][reg];
                }
    }

    // ---- fused el/er epilogue ----
#pragma unroll
    for (int mt = 0; mt < 2; ++mt) {
#pragma unroll
        for (int reg = 0; reg < 4; ++reg) {
            float pl[4], pr[4];
#pragma unroll
            for (int h = 0; h < 4; ++h) {
                const float v0 = acc[mt][2 * h][reg];
                const float v1 = acc[mt][2 * h + 1][reg];
                pl[h] = v0 * alw[2 * h] + v1 * alw[2 * h + 1];
                pr[h] = v0 * arw[2 * h] + v1 * arw[2 * h + 1];
            }
#pragma unroll
            for (int s = 1; s < 16; s <<= 1) {
#pragma unroll
                for (int h = 0; h < 4; ++h) {
                    pl[h] += __shfl_xor(pl[h], s);
                    pr[h] += __shfl_xor(pr[h], s);
                }
            }
            if (frow == 0) {
                const int r = row0 + wv * 32 + mt * 16 + (lane >> 4) * 4 + reg;
                if (r < N) {
                    *(float4*)(el + (size_t)r * NH) = make_float4(pl[0], pl[1], pl[2], pl[3]);
                    *(float4*)(er + (size_t)r * NH) = make_float4(pr[0], pr[1], pr[2], pr[3]);
                }
            }
        }
    }
}

// ---------------------------------------------------------------------------
// Sub-barrier among the NCSR blocks of csr_chain_k (validated in R5: passed).
// Release on arrival makes prior plain stores visible; relaxed spin; acquire
// after passing. Co-residency: grid = NCSR = 256 <= CU count, tiny LDS/VGPR
// -> >=1 block/CU always -> all participants resident -> no deadlock.
// ---------------------------------------------------------------------------
__device__ __forceinline__ void subbar(int* bar, int target) {
    __syncthreads();
    if (threadIdx.x == 0) {
        __hip_atomic_fetch_add(bar, 1, __ATOMIC_ACQ_REL, __HIP_MEMORY_SCOPE_AGENT);
        while (__hip_atomic_load(bar, __ATOMIC_RELAXED, __HIP_MEMORY_SCOPE_AGENT) < target)
            __builtin_amdgcn_s_sleep(16);
        (void)__hip_atomic_load(bar, __ATOMIC_ACQUIRE, __HIP_MEMORY_SCOPE_AGENT);
    }
    __syncthreads();
}

// ---------------------------------------------------------------------------
// csr_chain_k: the 3 small CSR kernels (chunkscan -> bscatter -> csr finalize)
// merged into ONE dispatch, phases separated by subbar. CSR-only code in its
// own kernel -> no register coupling with the GEMM (R5 lesson). Logic is the
// R5-validated CSR role, verbatim.
// ---------------------------------------------------------------------------
__global__ __launch_bounds__(256) void csr_chain_k(const int* __restrict__ src,
                                                   const int* __restrict__ dst,
                                                   int* __restrict__ cnt,
                                                   int* __restrict__ total,
                                                   int* __restrict__ bstart,
                                                   int2* __restrict__ epair,
                                                   int* __restrict__ deg,
                                                   int* __restrict__ off,
                                                   int* __restrict__ ssrc,
                                                   int* __restrict__ ctrl,
                                                   int N, int E,
                                                   int nchunk, int nbucket) {
    __shared__ int cnt_l[512];   // bscatter cursors
    __shared__ int sl[256];      // scan scratch
    __shared__ int cl[256];      // csr node histogram
    __shared__ int lcur[256];    // csr local cursors
    const int cid = blockIdx.x;
    const int t = threadIdx.x;
    int* bar  = ctrl;
    int* gcur = ctrl + 1;

    // ---- phase 1: per-bucket scan over chunks + bucket segment alloc ----
    // cnt[c][b] <- exclusive prefix; total[b] = bucket size; bstart[b] via one
    // global atomicAdd per bucket (segment order arbitrary but consistent).
    for (int b = cid; b < nbucket; b += NCSR) {
        const int x = (t < nchunk) ? cnt[(size_t)t * nbucket + b] : 0;
        sl[t] = x;
        __syncthreads();
        int v = x;
        for (int s = 1; s < 256; s <<= 1) {
            const int add = (t >= s) ? sl[t - s] : 0;
            __syncthreads();
            v += add;
            sl[t] = v;
            __syncthreads();
        }
        if (t < nchunk) cnt[(size_t)t * nbucket + b] = v - x;
        if (t == 255) {
            total[b] = v;
            bstart[b] = atomicAdd(gcur, v);
        }
        __syncthreads();
    }
    subbar(bar, NCSR * 1);

    // ---- phase 2: coarse scatter into bucket-major (src,dst) pairs ----
    for (int c = cid; c < nchunk; c += NCSR) {
        for (int j = t; j < 512; j += 256)
            cnt_l[j] = (j < nbucket) ? bstart[j] + cnt[(size_t)c * nbucket + j] : 0;
        __syncthreads();
        const int e0 = c * CHUNK;
#pragma unroll
        for (int k = 0; k < CHUNK / 256; ++k) {
            const int i = e0 + k * 256 + t;
            if (i < E) {
                const int d = dst[i];
                const int p = atomicAdd(&cnt_l[d >> 8], 1);
                epair[p] = make_int2(src[i], d);
            }
        }
        __syncthreads();
    }
    subbar(bar, NCSR * 2);

    // ---- phase 3: per-bucket CSR finalize (deg, absolute off, ssrc) ----
    for (int b = cid; b < nbucket; b += NCSR) {
        const int seg0 = bstart[b];
        const int tb   = total[b];
        cl[t] = 0;
        __syncthreads();
        for (int i = seg0 + t; i < seg0 + tb; i += 256)
            atomicAdd(&cl[epair[i].y & 255], 1);
        __syncthreads();
        const int x2 = cl[t];
        sl[t] = x2;
        __syncthreads();
        int v2 = x2;
        for (int s = 1; s < 256; s <<= 1) {
            const int add = (t >= s) ? sl[t - s] : 0;
            __syncthreads();
            v2 += add;
            sl[t] = v2;
            __syncthreads();
        }
        const int loff = v2 - x2;
        const int node = b * BNODES + t;
        if (node < N) {
            deg[node] = x2;
            off[node] = seg0 + loff;    // ABSOLUTE
        }
        lcur[t] = loff;
        __syncthreads();
        for (int i = seg0 + t; i < seg0 + tb; i += 256) {
            const int2 e = epair[i];
            const int p = atomicAdd(&lcur[e.y & 255], 1);
            ssrc[seg0 + p] = e.x;
        }
        __syncthreads();
    }
}

// ---------------------------------------------------------------------------
// Aggregation: one wave per dst node. UNCHANGED (measured at its gather-
// pattern roofline: ~245 MB beyond-L2 traffic at ~3.9 TB/s, ~77us).
// ---------------------------------------------------------------------------
__global__ __launch_bounds__(64) void aggregate_k(const __bf16* __restrict__ ft,
                                                  const float* __restrict__ el,
                                                  const float* __restrict__ er,
                                                  const int* __restrict__ deg,
                                                  const int* __restrict__ off,
                                                  const int* __restrict__ ssrc,
                                                  float* __restrict__ out, int N) {
    const int n = blockIdx.x;
    const int lane = threadIdx.x;
    const int il = lane & 15;       // feature group: f = il*8 .. il*8+7
    const int q  = lane >> 4;       // edge slot within group of 4
    const int h  = il >> 2;         // head of this feature group
    float4* outp = (float4*)(out + (size_t)n * HD);
    const int dn = deg[n];
    if (dn == 0) {
        if (q < 2) outp[il * 2 + q] = make_float4(0.f, 0.f, 0.f, 0.f);
        return;
    }
    const int start = off[n];
    const float4 er4 = *(const float4*)(er + (size_t)n * NH);

    __shared__ float a_lds[64 * NH];
    __shared__ int   s_lds[64];
    float4 ssum = make_float4(0.f, 0.f, 0.f, 0.f);
    float acc[8];
#pragma unroll
    for (int i = 0; i < 8; ++i) acc[i] = 0.f;

    for (int c0 = 0; c0 < dn; c0 += 64) {
        const int j = c0 + lane;
        float4 a = make_float4(0.f, 0.f, 0.f, 0.f);
        int sv = 0;
        if (j < dn) {
            sv = ssrc[start + j];
            float4 e = *(const float4*)(el + (size_t)sv * NH);
            e.x += er4.x; e.y += er4.y; e.z += er4.z; e.w += er4.w;
            e.x = e.x >= 0.f ? e.x : 0.2f * e.x;
            e.y = e.y >= 0.f ? e.y : 0.2f * e.y;
            e.z = e.z >= 0.f ? e.z : 0.2f * e.z;
            e.w = e.w >= 0.f ? e.w : 0.2f * e.w;
            a.x = __expf(e.x); a.y = __expf(e.y);
            a.z = __expf(e.z); a.w = __expf(e.w);
            ssum.x += a.x; ssum.y += a.y; ssum.z += a.z; ssum.w += a.w;
        }
        s_lds[lane] = sv;
        *(float4*)(a_lds + lane * NH) = a;
        __syncthreads();
        const int cnt2 = min(64, dn - c0);
        for (int j2 = 0; j2 < cnt2; j2 += 8) {   // 8 edges/iter (2 groups of 4)
            const int e0 = j2 + q;
            const int e1 = j2 + 4 + q;
            const int sv0 = s_lds[e0];
            const int sv1 = s_lds[e1];
            const float a0 = a_lds[e0 * NH + h];
            const float a1 = a_lds[e1 * NH + h];
            const bf16x8 f0 = *(const bf16x8*)(ft + (size_t)sv0 * HD + il * 8);
            const bf16x8 f1 = *(const bf16x8*)(ft + (size_t)sv1 * HD + il * 8);
#pragma unroll
            for (int k = 0; k < 8; ++k) acc[k] = fmaf(a0, (float)f0[k], acc[k]);
#pragma unroll
            for (int k = 0; k < 8; ++k) acc[k] = fmaf(a1, (float)f1[k], acc[k]);
        }
        __syncthreads();
    }
#pragma unroll
    for (int s = 1; s < 64; s <<= 1) {
        ssum.x += __shfl_xor(ssum.x, s);
        ssum.y += __shfl_xor(ssum.y, s);
        ssum.z += __shfl_xor(ssum.z, s);
        ssum.w += __shfl_xor(ssum.w, s);
    }
#pragma unroll
    for (int k = 0; k < 8; ++k) {
        acc[k] += __shfl_xor(acc[k], 16);
        acc[k] += __shfl_xor(acc[k], 32);
    }
    const float sumh = (h == 0) ? ssum.x : (h == 1) ? ssum.y : (h == 2) ? ssum.z : ssum.w;
    const float inv = 1.f / sumh;
    if (q < 2) {
        const int b = q * 4;
        outp[il * 2 + q] = make_float4(acc[b] * inv, acc[b + 1] * inv,
                                       acc[b + 2] * inv, acc[b + 3] * inv);
    }
}

// ---------------------------------------------------------------------------
extern "C" void kernel_launch(void* const* d_in, const int* in_sizes, int n_in,
                              void* d_out, int out_size, void* d_ws, size_t ws_size,
                              hipStream_t stream) {
    const float* feat   = (const float*)d_in[0];
    const float* fc_w   = (const float*)d_in[1];
    const float* attn_l = (const float*)d_in[2];
    const float* attn_r = (const float*)d_in[3];
    const int*   src    = (const int*)d_in[4];
    const int*   dst    = (const int*)d_in[5];
    const int N = in_sizes[0] / IN_F;
    const int E = in_sizes[4];
    float* out = (float*)d_out;

    const int ntiles  = (N + GM - 1) / GM;          // 782
    const int nchunk  = (E + CHUNK - 1) / CHUNK;    // 196 (<=256 required)
    const int nbucket = (N + BNODES - 1) / BNODES;  // 391 (<=512 required)

    char* wp = (char*)d_ws;
    __bf16* ft = (__bf16*)wp; wp += (size_t)N * HD * 2;           // 25.6 MB
    float* el  = (float*)wp; wp += (size_t)N * NH * 4;            // 1.6 MB
    float* er  = (float*)wp; wp += (size_t)N * NH * 4;            // 1.6 MB
    int* deg   = (int*)wp;   wp += (size_t)N * 4;                 // 0.4 MB
    int* off   = (int*)wp;   wp += (size_t)N * 4;                 // 0.4 MB
    int* cnt   = (int*)wp;   wp += (size_t)nchunk * nbucket * 4;  // ~0.3 MB
    int* total = (int*)wp;   wp += 2048;
    int* bstart= (int*)wp;   wp += 2048;
    int* ctrl  = (int*)wp;   wp += 64;                            // [bar, gcur]
    int* ssrc  = (int*)wp;   wp += (size_t)E * 4;                 // 6.4 MB
    int2* epair = (int2*)wp; wp += (size_t)E * 8;                 // 12.8 MB
    __bf16* wfrag = (__bf16*)wp; wp += (size_t)HD * IN_F * 2;     // 64 KB

    init_k<<<dim3(1), dim3(256), 0, stream>>>(fc_w, wfrag, ctrl);
    gemm_fused<<<dim3(ntiles + nchunk), dim3(256), 0, stream>>>(
        feat, wfrag, attn_l, attn_r, dst, ft, el, er, cnt, N, E, ntiles, nbucket);
    csr_chain_k<<<dim3(NCSR), dim3(256), 0, stream>>>(
        src, dst, cnt, total, bstart, epair, deg, off, ssrc, ctrl, N, E, nchunk, nbucket);
    aggregate_k<<<dim3(N), dim3(64), 0, stream>>>(ft, el, er, deg, off, ssrc, out, N);
}